// Round 2
// baseline (724.039 us; speedup 1.0000x reference)
//
#include <hip/hip_runtime.h>
#include <hip/hip_bf16.h>
#include <cstdint>

// GemmaAttention MI355X pipeline:
//   convH -> transW(x4) -> costab -> projGEMM(QKV) -> rope -> stats -> merge
//   -> weights+PV -> WoGEMM
// bf16 MFMA (16x16x32) everywhere; fp32 accumulate; fp32 outputs.

#define BB 2
#define SS 2048
#define HIDD 2048
#define NHH 8
#define HDD 256
#define L2E 1.44269504088896340736f
#define QSCALE 0.0625f  // 1/sqrt(256)

typedef float f32x4 __attribute__((ext_vector_type(4)));
typedef short short8 __attribute__((ext_vector_type(8)));
typedef __bf16 bf16x8 __attribute__((ext_vector_type(8)));
typedef __attribute__((address_space(1))) void gvoid;
typedef __attribute__((address_space(3))) void svoid;

__device__ __forceinline__ ushort f2bf(float f){
  union { float f; uint32_t u; } v; v.f = f;
  uint32_t r = (v.u + 0x7fffu + ((v.u >> 16) & 1u)) >> 16;
  return (ushort)r;
}
__device__ __forceinline__ float bf2f(ushort u){
  union { uint32_t u; float f; } v; v.u = ((uint32_t)u) << 16;
  return v.f;
}
__device__ __forceinline__ void gld_lds16(const ushort* gp, ushort* lp){
  __builtin_amdgcn_global_load_lds((gvoid*)gp, (svoid*)lp, 16, 0, 0);
}
__device__ __forceinline__ f32x4 mfma16(short8 a, short8 b, f32x4 c){
  return __builtin_amdgcn_mfma_f32_16x16x32_bf16(
      __builtin_bit_cast(bf16x8, a), __builtin_bit_cast(bf16x8, b), c, 0, 0, 0);
}

// ---------------- convert H fp32 -> bf16 ----------------
__global__ void k_convH(const float* __restrict__ Hf, ushort* __restrict__ Hb){
  const int n4 = (BB*SS*HIDD) >> 2;
  for (int i = blockIdx.x*256 + threadIdx.x; i < n4; i += gridDim.x*256){
    float4 v = ((const float4*)Hf)[i];
    ushort4 o; o.x=f2bf(v.x); o.y=f2bf(v.y); o.z=f2bf(v.z); o.w=f2bf(v.w);
    ((ushort4*)Hb)[i] = o;
  }
}

// ---------------- transpose-convert W[k][n] fp32 -> Wt[n][k] bf16 (LD 2048) ----
__global__ __launch_bounds__(256) void k_transW(const float* __restrict__ W,
                                                ushort* __restrict__ Wt,
                                                int N, int rowOff){
  __shared__ float t[64][65];
  const int n0 = blockIdx.x * 64, k0 = blockIdx.y * 64;
  const int tid = threadIdx.x;
  const int r = tid >> 4, c4 = (tid & 15) << 2;
  #pragma unroll
  for (int i = 0; i < 4; ++i){
    int rr = r + i*16;
    float4 v = *(const float4*)&W[(size_t)(k0 + rr) * N + n0 + c4];
    t[rr][c4] = v.x; t[rr][c4+1] = v.y; t[rr][c4+2] = v.z; t[rr][c4+3] = v.w;
  }
  __syncthreads();
  #pragma unroll
  for (int i = 0; i < 4; ++i){
    int nn = r + i*16;
    ushort4 o;
    o.x = f2bf(t[c4  ][nn]); o.y = f2bf(t[c4+1][nn]);
    o.z = f2bf(t[c4+2][nn]); o.w = f2bf(t[c4+3][nn]);
    *(ushort4*)&Wt[(size_t)(rowOff + n0 + nn) * 2048 + k0 + c4] = o;
  }
}

// ---------------- RoPE cos/sin table ----------------
__global__ void k_costab(const int* __restrict__ pos, float2* __restrict__ cs){
  int i = blockIdx.x*256 + threadIdx.x;       // < B*S*128
  int d = i & 127, bs = i >> 7;
  float p = (float)pos[bs];
  // inv_freq = 10000^(-2d/256) = 2^(-2d/256 * log2(10000))
  float inv = exp2f(-(float)(2*d) * (13.287712379549449f / 256.0f));
  float f = p * inv;
  cs[i] = make_float2(cosf(f), sinf(f));
}

// ---------------- RoPE in place on Q (with score scale) and K --------------
__global__ void k_rope(ushort* __restrict__ Qr, ushort* __restrict__ Kr,
                       const float2* __restrict__ cs){
  const int NQ = BB*SS*NHH*128;
  int i = blockIdx.x*256 + threadIdx.x;
  if (i < NQ){
    int d = i & 127, h = (i >> 7) & 7, bs = i >> 10;
    ushort* p = Qr + (size_t)bs*2048 + h*256 + d;
    float2 c = cs[bs*128 + d];
    float x1 = bf2f(p[0]), x2 = bf2f(p[128]);
    p[0]   = f2bf((x1*c.x - x2*c.y) * QSCALE);
    p[128] = f2bf((x2*c.x + x1*c.y) * QSCALE);
  } else if (i < NQ + BB*SS*128){
    int j = i - NQ;
    int d = j & 127, bs = j >> 7;
    ushort* p = Kr + (size_t)bs*256 + d;
    float2 c = cs[bs*128 + d];
    float x1 = bf2f(p[0]), x2 = bf2f(p[128]);
    p[0]   = f2bf(x1*c.x - x2*c.y);
    p[128] = f2bf(x2*c.x + x1*c.y);
  }
}

// ---------------- m97-style 128x128 bf16 GEMM, BK=32 ----------------
// mode 0: C fp32 -> Cf[row*2048+n]
// mode 1: QKV scatter: n<2048 -> Qr bf16; n<2304 -> Kr; else -> Vt transposed
__global__ __launch_bounds__(256) void k_gemm(const ushort* __restrict__ A,
                                              const ushort* __restrict__ Bt,
                                              int Ksteps, int mode,
                                              float* __restrict__ Cf,
                                              ushort* __restrict__ Qr,
                                              ushort* __restrict__ Kr,
                                              ushort* __restrict__ Vt){
  __shared__ __align__(16) ushort As[128*32];
  __shared__ __align__(16) ushort Bs[128*32];
  const int tid = threadIdx.x;
  const int l = tid & 63, w = tid >> 6;
  const int lr = l & 15, lg = l >> 4;
  const int wr = (w >> 1) * 64, wc = (w & 1) * 64;
  const int m0 = blockIdx.y * 128, n0 = blockIdx.x * 128;
  f32x4 acc[4][4] = {};
  for (int kt = 0; kt < Ksteps; ++kt){
    const int kb = kt * 32;
    #pragma unroll
    for (int t = 0; t < 2; ++t){
      int r = t*64 + (tid >> 2), g = tid & 3;
      int gl = g ^ ((r >> 1) & 3);          // 2-way-conflict chunk swizzle
      gld_lds16(A  + (size_t)(m0 + r) * 2048 + kb + gl*8, As + (t*256 + (tid & ~63))*8);
      gld_lds16(Bt + (size_t)(n0 + r) * 2048 + kb + gl*8, Bs + (t*256 + (tid & ~63))*8);
    }
    __syncthreads();
    short8 af[4], bf[4];
    #pragma unroll
    for (int mi = 0; mi < 4; ++mi){
      int r = wr + mi*16 + lr;
      af[mi] = *(const short8*)&As[r*32 + ((lg ^ ((r>>1)&3)) << 3)];
    }
    #pragma unroll
    for (int ni = 0; ni < 4; ++ni){
      int r = wc + ni*16 + lr;
      bf[ni] = *(const short8*)&Bs[r*32 + ((lg ^ ((r>>1)&3)) << 3)];
    }
    #pragma unroll
    for (int mi = 0; mi < 4; ++mi)
      #pragma unroll
      for (int ni = 0; ni < 4; ++ni)
        acc[mi][ni] = mfma16(af[mi], bf[ni], acc[mi][ni]);
    __syncthreads();
  }
  #pragma unroll
  for (int mi = 0; mi < 4; ++mi){
    #pragma unroll
    for (int ni = 0; ni < 4; ++ni){
      #pragma unroll
      for (int r = 0; r < 4; ++r){
        int row = m0 + wr + mi*16 + lg*4 + r;
        int nn  = n0 + wc + ni*16 + lr;
        float v = acc[mi][ni][r];
        if (mode == 0){
          Cf[(size_t)row * 2048 + nn] = v;
        } else {
          if (nn < 2048)      Qr[(size_t)row*2048 + nn] = f2bf(v);
          else if (nn < 2304) Kr[(size_t)row*256 + (nn - 2048)] = f2bf(v);
          else { int d = nn - 2304;
                 Vt[((size_t)(row >> 11) * 256 + d) * 2048 + (row & 2047)] = f2bf(v); }
        }
      }
    }
  }
}

// ---------------- pass 1: softmax stats (online m,l), k-split x4 ----------
__global__ __launch_bounds__(256) void k_stats(const ushort* __restrict__ Qr,
                                               const ushort* __restrict__ Kr,
                                               float* __restrict__ mpart,
                                               float* __restrict__ lpart){
  __shared__ __align__(16) ushort Ks[32*256];
  const int qt = blockIdx.x, ksp = blockIdx.y, bh = blockIdx.z;
  const int b = bh >> 3, h = bh & 7;
  const int q0 = qt * 64;
  const int nkt = (q0 + 64) >> 5;
  const int per = (nkt + 3) >> 2;
  const int t0 = ksp * per;
  const int t1 = min(nkt, t0 + per);
  const int tid = threadIdx.x;
  const int l = tid & 63, w = tid >> 6;
  const int lr = l & 15, lg = l >> 4;
  short8 qf[8];
  const ushort* qbase = Qr + ((size_t)(b*SS) + q0 + w*16 + lr) * 2048 + h*256;
  #pragma unroll
  for (int dc = 0; dc < 8; ++dc) qf[dc] = *(const short8*)&qbase[dc*32 + lg*8];
  float mrun[4], lrun[4];
  #pragma unroll
  for (int r = 0; r < 4; ++r){ mrun[r] = -3e38f; lrun[r] = 0.f; }
  for (int kt = t0; kt < t1; ++kt){
    const int k0 = kt * 32;
    #pragma unroll
    for (int t = 0; t < 4; ++t){
      int idx = t*256 + tid;
      int r = idx >> 5, g = idx & 31;
      int gl = g ^ (r & 7);                 // 512B-row swizzle
      gld_lds16(Kr + ((size_t)(b*SS) + k0 + r) * 256 + gl*8, Ks + (t*256 + (tid & ~63))*8);
    }
    __syncthreads();
    f32x4 sc0 = {0.f,0.f,0.f,0.f}, sc1 = {0.f,0.f,0.f,0.f};
    const int kr0 = lr, kr1 = 16 + lr;
    #pragma unroll
    for (int dc = 0; dc < 8; ++dc){
      short8 b0 = *(const short8*)&Ks[kr0*256 + ((dc*32 + lg*8) ^ ((kr0 & 7) << 3))];
      sc0 = mfma16(qf[dc], b0, sc0);
    }
    #pragma unroll
    for (int dc = 0; dc < 8; ++dc){
      short8 b1 = *(const short8*)&Ks[kr1*256 + ((dc*32 + lg*8) ^ ((kr1 & 7) << 3))];
      sc1 = mfma16(qf[dc], b1, sc1);
    }
    __syncthreads();
    #pragma unroll
    for (int r = 0; r < 4; ++r){
      const int qq = q0 + w*16 + lg*4 + r;
      float s0 = (k0 + lr       <= qq) ? sc0[r] : -3e38f;
      float s1 = (k0 + 16 + lr  <= qq) ? sc1[r] : -3e38f;
      float mx = fmaxf(s0, s1);
      #pragma unroll
      for (int d = 1; d < 16; d <<= 1) mx = fmaxf(mx, __shfl_xor(mx, d, 64));
      float mnew = fmaxf(mrun[r], mx);
      if (mnew > -1e37f){                    // uniform within 16-lane col group
        float ps = exp2f((s0 - mnew) * L2E) + exp2f((s1 - mnew) * L2E);
        #pragma unroll
        for (int d = 1; d < 16; d <<= 1) ps += __shfl_xor(ps, d, 64);
        lrun[r] = lrun[r] * exp2f((mrun[r] - mnew) * L2E) + ps;
        mrun[r] = mnew;
      }
    }
  }
  if (lr == 0){
    #pragma unroll
    for (int r = 0; r < 4; ++r){
      int qq = q0 + w*16 + lg*4 + r;
      size_t sidx = (size_t)ksp * (BB*NHH*SS) + (size_t)bh * SS + qq;
      mpart[sidx] = mrun[r];
      lpart[sidx] = lrun[r];
    }
  }
}

__global__ void k_merge(const float* __restrict__ mpart, const float* __restrict__ lpart,
                        float* __restrict__ mfin, float* __restrict__ invl){
  const int N = BB*NHH*SS;
  int i = blockIdx.x * 256 + threadIdx.x;
  if (i >= N) return;
  float m = -3e38f;
  #pragma unroll
  for (int s = 0; s < 4; ++s) m = fmaxf(m, mpart[s*N + i]);
  float lsum = 0.f;
  #pragma unroll
  for (int s = 0; s < 4; ++s){
    float ls = lpart[s*N + i];
    lsum += (ls > 0.f) ? ls * exp2f((mpart[s*N + i] - m) * L2E) : 0.f;
  }
  mfin[i] = m;
  invl[i] = 1.0f / lsum;
}

// ---------------- pass 2: attn weights write + PV ----------------
__global__ __launch_bounds__(256) void k_attn2(const ushort* __restrict__ Qr,
                                               const ushort* __restrict__ Kr,
                                               const ushort* __restrict__ Vt,
                                               const float* __restrict__ mfin,
                                               const float* __restrict__ invl,
                                               float* __restrict__ Wout,
                                               ushort* __restrict__ Ows){
  __shared__ __align__(16) ushort Ks[32*256];
  __shared__ __align__(16) ushort Vs[256*32];
  __shared__ __align__(16) ushort Ps[4][16*32];
  const int qt = (int)gridDim.x - 1 - (int)blockIdx.x;   // big q-tiles first
  const int bh = blockIdx.y;
  const int b = bh >> 3, h = bh & 7;
  const int q0 = qt * 64;
  const int tid = threadIdx.x;
  const int l = tid & 63, w = tid >> 6;
  const int lr = l & 15, lg = l >> 4;
  short8 qf[8];
  const ushort* qbase = Qr + ((size_t)(b*SS) + q0 + w*16 + lr) * 2048 + h*256;
  #pragma unroll
  for (int dc = 0; dc < 8; ++dc) qf[dc] = *(const short8*)&qbase[dc*32 + lg*8];
  float mrow[4], il[4];
  #pragma unroll
  for (int r = 0; r < 4; ++r){
    int qq = q0 + w*16 + lg*4 + r;
    mrow[r] = mfin[bh*SS + qq];
    il[r]   = invl[bh*SS + qq];
  }
  f32x4 oacc[16] = {};
  const int nkt = (q0 + 64) >> 5;
  for (int kt = 0; kt < nkt; ++kt){
    const int k0 = kt * 32;
    #pragma unroll
    for (int t = 0; t < 4; ++t){
      int idx = t*256 + tid;
      int r = idx >> 5, g = idx & 31;
      int gl = g ^ (r & 7);
      gld_lds16(Kr + ((size_t)(b*SS) + k0 + r) * 256 + gl*8, Ks + (t*256 + (tid & ~63))*8);
    }
    #pragma unroll
    for (int t = 0; t < 4; ++t){
      int idx = t*256 + tid;
      int r = idx >> 2, g = idx & 3;        // r = d-row of Vt tile
      int gl = g ^ ((r >> 1) & 3);
      gld_lds16(Vt + ((size_t)b*256 + r) * 2048 + k0 + gl*8, Vs + (t*256 + (tid & ~63))*8);
    }
    __syncthreads();
    f32x4 sc0 = {0.f,0.f,0.f,0.f}, sc1 = {0.f,0.f,0.f,0.f};
    const int kr0 = lr, kr1 = 16 + lr;
    #pragma unroll
    for (int dc = 0; dc < 8; ++dc){
      short8 b0 = *(const short8*)&Ks[kr0*256 + ((dc*32 + lg*8) ^ ((kr0 & 7) << 3))];
      sc0 = mfma16(qf[dc], b0, sc0);
    }
    #pragma unroll
    for (int dc = 0; dc < 8; ++dc){
      short8 b1 = *(const short8*)&Ks[kr1*256 + ((dc*32 + lg*8) ^ ((kr1 & 7) << 3))];
      sc1 = mfma16(qf[dc], b1, sc1);
    }
    // p = exp(s - m); write attn = p/l; stash p (bf16) for PV
    #pragma unroll
    for (int r = 0; r < 4; ++r){
      const int qq = q0 + w*16 + lg*4 + r;
      const int kk0 = k0 + lr, kk1 = k0 + 16 + lr;
      float p0 = (kk0 <= qq) ? exp2f((sc0[r] - mrow[r]) * L2E) : 0.f;
      float p1 = (kk1 <= qq) ? exp2f((sc1[r] - mrow[r]) * L2E) : 0.f;
      float* wrp = Wout + ((size_t)bh * SS + qq) * SS;
      wrp[kk0] = p0 * il[r];
      wrp[kk1] = p1 * il[r];
      int row = lg*4 + r;
      int sw = ((row >> 1) & 3) << 3;
      Ps[w][row*32 + (lr ^ sw)]        = f2bf(p0);
      Ps[w][row*32 + ((16 + lr) ^ sw)] = f2bf(p1);
    }
    // PV: out[16q][256d] += P[16q][32k] x V[32k][256d]
    short8 pa = *(const short8*)&Ps[w][lr*32 + ((lg*8) ^ (((lr >> 1) & 3) << 3))];
    #pragma unroll
    for (int nf = 0; nf < 16; ++nf){
      int dr = nf*16 + lr;
      short8 vb = *(const short8*)&Vs[dr*32 + ((lg*8) ^ (((dr >> 1) & 3) << 3))];
      oacc[nf] = mfma16(pa, vb, oacc[nf]);
    }
    __syncthreads();
  }
  // zero-fill strictly-above-block columns (exact zeros in reference too)
  const int zc0 = q0 + 64;
  if (zc0 < SS){
    const int quads = (SS - zc0) >> 2;
    const float4 z4 = make_float4(0.f, 0.f, 0.f, 0.f);
    for (int rr = w; rr < 64; rr += 4){
      float* rowp = Wout + ((size_t)bh*SS + q0 + rr)*SS + zc0;
      for (int c = l; c < quads; c += 64)
        *(float4*)&rowp[c*4] = z4;
    }
  }
  // write PV result (scaled by 1/l) as bf16 rows (b,s) x cols h*256+d
  #pragma unroll
  for (int nf = 0; nf < 16; ++nf){
    #pragma unroll
    for (int r = 0; r < 4; ++r){
      int qq = q0 + w*16 + lg*4 + r;
      int d  = nf*16 + lr;
      Ows[((size_t)(b*SS) + qq)*2048 + h*256 + d] = f2bf(oacc[nf][r] * il[r]);
    }
  }
}

// ---------------- host launch ----------------
extern "C" void kernel_launch(void* const* d_in, const int* in_sizes, int n_in,
                              void* d_out, int out_size, void* d_ws, size_t ws_size,
                              hipStream_t stream){
  const float* H  = (const float*)d_in[0];
  const int*  pos = (const int*)d_in[2];
  const float* Wq = (const float*)d_in[3];
  const float* Wk = (const float*)d_in[4];
  const float* Wv = (const float*)d_in[5];
  const float* Wo = (const float*)d_in[6];
  float* out = (float*)d_out;
  float* Wts = out + (size_t)BB*SS*HIDD;          // attn_weights region (also early scratch)

  // Scratch inside the (later fully overwritten) weights region: Hb 16MB + Wt 10MB
  ushort* Hb = (ushort*)Wts;
  ushort* Wt = Hb + (size_t)BB*SS*HIDD;

  char* ws = (char*)d_ws;
  size_t off = 0;
  auto alloc = [&](size_t bytes)->char*{
    char* p = ws + off; off += (bytes + 255) & ~(size_t)255; return p;
  };
  ushort* Wot   = (ushort*)alloc((size_t)2048*2048*2);
  ushort* Qr    = (ushort*)alloc((size_t)BB*SS*NHH*HDD*2);
  ushort* Kr    = (ushort*)alloc((size_t)BB*SS*HDD*2);
  ushort* Vt    = (ushort*)alloc((size_t)BB*HDD*SS*2);
  float2* cst   = (float2*)alloc((size_t)BB*SS*128*8);
  float*  mpart = (float*)alloc((size_t)4*BB*NHH*SS*4);
  float*  lpart = (float*)alloc((size_t)4*BB*NHH*SS*4);
  float*  mfin  = (float*)alloc((size_t)BB*NHH*SS*4);
  float*  invl  = (float*)alloc((size_t)BB*NHH*SS*4);
  ushort* Ows   = (ushort*)alloc((size_t)BB*SS*NHH*HDD*2);
  (void)ws_size; (void)in_sizes; (void)n_in; (void)out_size;

  k_convH<<<2048, 256, 0, stream>>>(H, Hb);
  k_transW<<<dim3(32,32), 256, 0, stream>>>(Wq, Wt, 2048, 0);
  k_transW<<<dim3(4,32),  256, 0, stream>>>(Wk, Wt, 256, 2048);
  k_transW<<<dim3(4,32),  256, 0, stream>>>(Wv, Wt, 256, 2304);
  k_transW<<<dim3(32,32), 256, 0, stream>>>(Wo, Wot, 2048, 0);
  k_costab<<<(BB*SS*128)/256, 256, 0, stream>>>(pos, cst);
  // [Q|K|V] = Hb @ Wt^T ; scatter epilogue
  k_gemm<<<dim3(20,32), 256, 0, stream>>>(Hb, Wt, 64, 1, nullptr, Qr, Kr, Vt);
  k_rope<<<(BB*SS*NHH*128 + BB*SS*128)/256, 256, 0, stream>>>(Qr, Kr, cst);
  k_stats<<<dim3(32,4,16), 256, 0, stream>>>(Qr, Kr, mpart, lpart);
  k_merge<<<(BB*NHH*SS)/256, 256, 0, stream>>>(mpart, lpart, mfin, invl);
  k_attn2<<<dim3(32,16), 256, 0, stream>>>(Qr, Kr, Vt, mfin, invl, Wts, Ows);
  // attn_output = Ows @ Wot^T
  k_gemm<<<dim3(16,32), 256, 0, stream>>>(Ows, Wot, 64, 0, out, nullptr, nullptr, nullptr);
}

// Round 4
// 711.558 us; speedup vs baseline: 1.0175x; 1.0175x over previous
//
#include <hip/hip_runtime.h>
#include <hip/hip_bf16.h>
#include <cstdint>

// GemmaAttention MI355X pipeline (R3/R4 resubmit):
//   prep(convH+costab) -> transAll -> projGEMM(QKV) -> transV -> rope
//   -> stats(KVBLK=64) -> merge -> weights+PV(KVBLK=64) -> WoGEMM
// bf16 MFMA (16x16x32); fp32 accumulate; fp32 outputs.

#define BB 2
#define SS 2048
#define HIDD 2048
#define NHH 8
#define HDD 256
#define L2E 1.44269504088896340736f
#define QSCALE 0.0625f  // 1/sqrt(256)

typedef float f32x4 __attribute__((ext_vector_type(4)));
typedef short short8 __attribute__((ext_vector_type(8)));
typedef __bf16 bf16x8 __attribute__((ext_vector_type(8)));
typedef __attribute__((address_space(1))) void gvoid;
typedef __attribute__((address_space(3))) void svoid;

__device__ __forceinline__ ushort f2bf(float f){
  union { float f; uint32_t u; } v; v.f = f;
  uint32_t r = (v.u + 0x7fffu + ((v.u >> 16) & 1u)) >> 16;
  return (ushort)r;
}
__device__ __forceinline__ float bf2f(ushort u){
  union { uint32_t u; float f; } v; v.u = ((uint32_t)u) << 16;
  return v.f;
}
__device__ __forceinline__ void gld_lds16(const ushort* gp, ushort* lp){
  __builtin_amdgcn_global_load_lds((gvoid*)gp, (svoid*)lp, 16, 0, 0);
}
__device__ __forceinline__ f32x4 mfma16(short8 a, short8 b, f32x4 c){
  return __builtin_amdgcn_mfma_f32_16x16x32_bf16(
      __builtin_bit_cast(bf16x8, a), __builtin_bit_cast(bf16x8, b), c, 0, 0, 0);
}

// ---------------- fused: convert H fp32->bf16 + RoPE cos/sin table ---------
__global__ void k_prep(const float* __restrict__ Hf, ushort* __restrict__ Hb,
                       const int* __restrict__ pos, float2* __restrict__ cs){
  const int n4 = (BB*SS*HIDD) >> 2;
  const int ncs = BB*SS*128;
  for (int i = blockIdx.x*256 + threadIdx.x; i < n4 + ncs; i += gridDim.x*256){
    if (i < n4){
      float4 v = ((const float4*)Hf)[i];
      ushort4 o; o.x=f2bf(v.x); o.y=f2bf(v.y); o.z=f2bf(v.z); o.w=f2bf(v.w);
      ((ushort4*)Hb)[i] = o;
    } else {
      int j = i - n4;
      int d = j & 127, bs = j >> 7;
      float p = (float)pos[bs];
      float inv = exp2f(-(float)(2*d) * (13.287712379549449f / 256.0f));
      float f = p * inv;
      cs[j] = make_float2(cosf(f), sinf(f));
    }
  }
}

// -------- fused transpose-convert of Wq/Wk/Wv/Wo: W[k][n] -> Wt[n][k] bf16 --
__global__ __launch_bounds__(256) void k_transAll(const float* __restrict__ Wq,
                                                  const float* __restrict__ Wk,
                                                  const float* __restrict__ Wv,
                                                  const float* __restrict__ Wo,
                                                  ushort* __restrict__ Wt,
                                                  ushort* __restrict__ Wot){
  __shared__ float t[64][65];
  const int z = blockIdx.x;
  const float* W; ushort* dst; int N, rowOff, loc, nbx;
  if (z < 1024){ W=Wq; dst=Wt;  N=2048; rowOff=0;    loc=z;      nbx=32; }
  else if (z < 1152){ W=Wk; dst=Wt; N=256; rowOff=2048; loc=z-1024; nbx=4; }
  else if (z < 1280){ W=Wv; dst=Wt; N=256; rowOff=2304; loc=z-1152; nbx=4; }
  else { W=Wo; dst=Wot; N=2048; rowOff=0; loc=z-1280; nbx=32; }
  const int n0 = (loc % nbx) * 64, k0 = (loc / nbx) * 64;
  const int tid = threadIdx.x;
  const int r = tid >> 4, c4 = (tid & 15) << 2;
  #pragma unroll
  for (int i = 0; i < 4; ++i){
    int rr = r + i*16;
    float4 v = *(const float4*)&W[(size_t)(k0 + rr) * N + n0 + c4];
    t[rr][c4] = v.x; t[rr][c4+1] = v.y; t[rr][c4+2] = v.z; t[rr][c4+3] = v.w;
  }
  __syncthreads();
  #pragma unroll
  for (int i = 0; i < 4; ++i){
    int nn = r + i*16;
    ushort4 o;
    o.x = f2bf(t[c4  ][nn]); o.y = f2bf(t[c4+1][nn]);
    o.z = f2bf(t[c4+2][nn]); o.w = f2bf(t[c4+3][nn]);
    *(ushort4*)&dst[(size_t)(rowOff + n0 + nn) * 2048 + k0 + c4] = o;
  }
}

// ---------------- RoPE in place on Q (with score scale) and K --------------
__global__ void k_rope(ushort* __restrict__ Qr, ushort* __restrict__ Kr,
                       const float2* __restrict__ cs){
  const int NQ = BB*SS*NHH*128;
  int i = blockIdx.x*256 + threadIdx.x;
  if (i < NQ){
    int d = i & 127, h = (i >> 7) & 7, bs = i >> 10;
    ushort* p = Qr + (size_t)bs*2048 + h*256 + d;
    float2 c = cs[bs*128 + d];
    float x1 = bf2f(p[0]), x2 = bf2f(p[128]);
    p[0]   = f2bf((x1*c.x - x2*c.y) * QSCALE);
    p[128] = f2bf((x2*c.x + x1*c.y) * QSCALE);
  } else if (i < NQ + BB*SS*128){
    int j = i - NQ;
    int d = j & 127, bs = j >> 7;
    ushort* p = Kr + (size_t)bs*256 + d;
    float2 c = cs[bs*128 + d];
    float x1 = bf2f(p[0]), x2 = bf2f(p[128]);
    p[0]   = f2bf(x1*c.x - x2*c.y);
    p[128] = f2bf(x2*c.x + x1*c.y);
  }
}

// ---------------- m97-style 128x128 bf16 GEMM, BK=32 ----------------
// mode 0: C fp32 -> Cf[row*2048+n]
// mode 1: QKV scatter: n<2048 -> Qr; n<2304 -> Kr; else -> Vr (row-major)
__global__ __launch_bounds__(256) void k_gemm(const ushort* __restrict__ A,
                                              const ushort* __restrict__ Bt,
                                              int Ksteps, int mode,
                                              float* __restrict__ Cf,
                                              ushort* __restrict__ Qr,
                                              ushort* __restrict__ Kr,
                                              ushort* __restrict__ Vr){
  __shared__ __align__(16) ushort As[128*32];
  __shared__ __align__(16) ushort Bs[128*32];
  const int tid = threadIdx.x;
  const int l = tid & 63, w = tid >> 6;
  const int lr = l & 15, lg = l >> 4;
  const int wr = (w >> 1) * 64, wc = (w & 1) * 64;
  const int m0 = blockIdx.y * 128, n0 = blockIdx.x * 128;
  f32x4 acc[4][4] = {};
  for (int kt = 0; kt < Ksteps; ++kt){
    const int kb = kt * 32;
    #pragma unroll
    for (int t = 0; t < 2; ++t){
      int r = t*64 + (tid >> 2), g = tid & 3;
      int gl = g ^ ((r >> 1) & 3);          // 2-way-conflict chunk swizzle
      gld_lds16(A  + (size_t)(m0 + r) * 2048 + kb + gl*8, As + (t*256 + (tid & ~63))*8);
      gld_lds16(Bt + (size_t)(n0 + r) * 2048 + kb + gl*8, Bs + (t*256 + (tid & ~63))*8);
    }
    __syncthreads();
    short8 af[4], bf[4];
    #pragma unroll
    for (int mi = 0; mi < 4; ++mi){
      int r = wr + mi*16 + lr;
      af[mi] = *(const short8*)&As[r*32 + ((lg ^ ((r>>1)&3)) << 3)];
    }
    #pragma unroll
    for (int ni = 0; ni < 4; ++ni){
      int r = wc + ni*16 + lr;
      bf[ni] = *(const short8*)&Bs[r*32 + ((lg ^ ((r>>1)&3)) << 3)];
    }
    #pragma unroll
    for (int mi = 0; mi < 4; ++mi)
      #pragma unroll
      for (int ni = 0; ni < 4; ++ni)
        acc[mi][ni] = mfma16(af[mi], bf[ni], acc[mi][ni]);
    __syncthreads();
  }
  #pragma unroll
  for (int mi = 0; mi < 4; ++mi){
    #pragma unroll
    for (int ni = 0; ni < 4; ++ni){
      #pragma unroll
      for (int r = 0; r < 4; ++r){
        int row = m0 + wr + mi*16 + lg*4 + r;
        int nn  = n0 + wc + ni*16 + lr;
        float v = acc[mi][ni][r];
        if (mode == 0){
          Cf[(size_t)row * 2048 + nn] = v;
        } else {
          if (nn < 2048)      Qr[(size_t)row*2048 + nn] = f2bf(v);
          else if (nn < 2304) Kr[(size_t)row*256 + (nn - 2048)] = f2bf(v);
          else                Vr[(size_t)row*256 + (nn - 2304)] = f2bf(v);
        }
      }
    }
  }
}

// ---------------- V transpose: Vr[b][s][d] -> Vt[b][d][s] ----------------
__global__ __launch_bounds__(256) void k_transV(const ushort* __restrict__ Vr,
                                                ushort* __restrict__ Vt){
  __shared__ ushort T[64][72];
  const int bidx = blockIdx.x;            // 2 b * 32 s-tiles * 4 d-tiles
  const int b = bidx >> 7, rest = bidx & 127;
  const int s0 = (rest >> 2) * 64, d0 = (rest & 3) * 64;
  const int tid = threadIdx.x;
  #pragma unroll
  for (int i = 0; i < 2; ++i){
    int idx = i*256 + tid;
    int r = idx >> 3, c = (idx & 7) * 8;
    short8 v = *(const short8*)&Vr[((size_t)(b*SS) + s0 + r)*256 + d0 + c];
    #pragma unroll
    for (int j = 0; j < 8; ++j) T[r][c + j] = (ushort)v[j];
  }
  __syncthreads();
  #pragma unroll
  for (int i = 0; i < 2; ++i){
    int idx = i*256 + tid;
    int dr = idx >> 3, c = (idx & 7) * 8;
    short8 o;
    #pragma unroll
    for (int j = 0; j < 8; ++j) o[j] = (short)T[c + j][dr];
    *(short8*)&Vt[((size_t)(b*256) + d0 + dr)*2048 + s0 + c] = o;
  }
}

// ---------------- pass 1: softmax stats (online m,l), KVBLK=64 ------------
__global__ __launch_bounds__(256) void k_stats(const ushort* __restrict__ Qr,
                                               const ushort* __restrict__ Kr,
                                               float* __restrict__ mpart,
                                               float* __restrict__ lpart){
  __shared__ __align__(16) ushort Ks[64*256];
  const int qt = blockIdx.x, ksp = blockIdx.y, bh = blockIdx.z;
  const int b = bh >> 3, h = bh & 7;
  const int q0 = qt * 64;
  const int nkt = (q0 + 64) >> 6;
  const int per = (nkt + 3) >> 2;
  const int t0 = ksp * per;
  const int t1 = min(nkt, t0 + per);
  const int tid = threadIdx.x;
  const int l = tid & 63, w = tid >> 6;
  const int lr = l & 15, lg = l >> 4;
  short8 qf[8];
  const ushort* qbase = Qr + ((size_t)(b*SS) + q0 + w*16 + lr) * 2048 + h*256;
  #pragma unroll
  for (int dc = 0; dc < 8; ++dc) qf[dc] = *(const short8*)&qbase[dc*32 + lg*8];
  float mrun[4], lrun[4];
  #pragma unroll
  for (int r = 0; r < 4; ++r){ mrun[r] = -3e38f; lrun[r] = 0.f; }
  for (int kt = t0; kt < t1; ++kt){
    const int k0 = kt * 64;
    #pragma unroll
    for (int t = 0; t < 8; ++t){
      int idx = t*256 + tid;
      int r = idx >> 5, g = idx & 31;
      int gl = g ^ (r & 7);                 // 512B-row swizzle
      gld_lds16(Kr + ((size_t)(b*SS) + k0 + r) * 256 + gl*8, Ks + (t*256 + (tid & ~63))*8);
    }
    __syncthreads();
    f32x4 sc[4] = {};
    #pragma unroll
    for (int j = 0; j < 4; ++j){
      const int krj = j*16 + lr;
      #pragma unroll
      for (int dc = 0; dc < 8; ++dc){
        short8 b8 = *(const short8*)&Ks[krj*256 + ((dc*32 + lg*8) ^ ((krj & 7) << 3))];
        sc[j] = mfma16(qf[dc], b8, sc[j]);
      }
    }
    __syncthreads();
    #pragma unroll
    for (int r = 0; r < 4; ++r){
      const int qq = q0 + w*16 + lg*4 + r;
      float s0 = (k0 + lr      <= qq) ? sc[0][r] : -3e38f;
      float s1 = (k0 + 16 + lr <= qq) ? sc[1][r] : -3e38f;
      float s2 = (k0 + 32 + lr <= qq) ? sc[2][r] : -3e38f;
      float s3 = (k0 + 48 + lr <= qq) ? sc[3][r] : -3e38f;
      float mx = fmaxf(fmaxf(s0, s1), fmaxf(s2, s3));
      #pragma unroll
      for (int d = 1; d < 16; d <<= 1) mx = fmaxf(mx, __shfl_xor(mx, d, 64));
      float mnew = fmaxf(mrun[r], mx);
      if (mnew > -1e37f){                    // uniform within 16-lane col group
        float ps = exp2f((s0 - mnew) * L2E) + exp2f((s1 - mnew) * L2E)
                 + exp2f((s2 - mnew) * L2E) + exp2f((s3 - mnew) * L2E);
        #pragma unroll
        for (int d = 1; d < 16; d <<= 1) ps += __shfl_xor(ps, d, 64);
        lrun[r] = lrun[r] * exp2f((mrun[r] - mnew) * L2E) + ps;
        mrun[r] = mnew;
      }
    }
  }
  if (lr == 0){
    #pragma unroll
    for (int r = 0; r < 4; ++r){
      int qq = q0 + w*16 + lg*4 + r;
      size_t sidx = (size_t)ksp * (BB*NHH*SS) + (size_t)bh * SS + qq;
      mpart[sidx] = mrun[r];
      lpart[sidx] = lrun[r];
    }
  }
}

__global__ void k_merge(const float* __restrict__ mpart, const float* __restrict__ lpart,
                        float* __restrict__ mfin, float* __restrict__ invl){
  const int N = BB*NHH*SS;
  int i = blockIdx.x * 256 + threadIdx.x;
  if (i >= N) return;
  float m = -3e38f;
  #pragma unroll
  for (int s = 0; s < 4; ++s) m = fmaxf(m, mpart[s*N + i]);
  float lsum = 0.f;
  #pragma unroll
  for (int s = 0; s < 4; ++s){
    float ls = lpart[s*N + i];
    lsum += (ls > 0.f) ? ls * exp2f((mpart[s*N + i] - m) * L2E) : 0.f;
  }
  mfin[i] = m;
  invl[i] = 1.0f / lsum;
}

// ---------------- pass 2: attn weights write + PV, KVBLK=64 ----------------
__global__ __launch_bounds__(256) void k_attn2(const ushort* __restrict__ Qr,
                                               const ushort* __restrict__ Kr,
                                               const ushort* __restrict__ Vt,
                                               const float* __restrict__ mfin,
                                               const float* __restrict__ invl,
                                               float* __restrict__ Wout,
                                               ushort* __restrict__ Ows){
  __shared__ __align__(16) ushort Ks[64*256];   // [k(64)][d(256)] swz chunk^(r&7)
  __shared__ __align__(16) ushort Vs[256*64];   // [d(256)][k(64)] swz chunk^(r&7)
  __shared__ __align__(16) ushort Ps[4][16*64]; // per-wave P, swz chunk^(row&7)
  const int qt = (int)gridDim.x - 1 - (int)blockIdx.x;   // big q-tiles first
  const int bh = blockIdx.y;
  const int b = bh >> 3, h = bh & 7;
  const int q0 = qt * 64;
  const int tid = threadIdx.x;
  const int l = tid & 63, w = tid >> 6;
  const int lr = l & 15, lg = l >> 4;
  short8 qf[8];
  const ushort* qbase = Qr + ((size_t)(b*SS) + q0 + w*16 + lr) * 2048 + h*256;
  #pragma unroll
  for (int dc = 0; dc < 8; ++dc) qf[dc] = *(const short8*)&qbase[dc*32 + lg*8];
  float mrow[4], il[4];
  #pragma unroll
  for (int r = 0; r < 4; ++r){
    int qq = q0 + w*16 + lg*4 + r;
    mrow[r] = mfin[bh*SS + qq];
    il[r]   = invl[bh*SS + qq];
  }
  f32x4 oacc[16] = {};
  const int nkt = (q0 + 64) >> 6;
  for (int kt = 0; kt < nkt; ++kt){
    const int k0 = kt * 64;
    #pragma unroll
    for (int t = 0; t < 8; ++t){
      int idx = t*256 + tid;
      int r = idx >> 5, g = idx & 31;
      int gl = g ^ (r & 7);
      gld_lds16(Kr + ((size_t)(b*SS) + k0 + r) * 256 + gl*8, Ks + (t*256 + (tid & ~63))*8);
    }
    #pragma unroll
    for (int t = 0; t < 8; ++t){
      int idx = t*256 + tid;
      int r = idx >> 3, g = idx & 7;        // r = d-row of Vt tile (128B rows)
      int gl = g ^ (r & 7);
      gld_lds16(Vt + ((size_t)b*256 + r) * 2048 + k0 + gl*8, Vs + (t*256 + (tid & ~63))*8);
    }
    __syncthreads();
    f32x4 sc[4] = {};
    #pragma unroll
    for (int j = 0; j < 4; ++j){
      const int krj = j*16 + lr;
      #pragma unroll
      for (int dc = 0; dc < 8; ++dc){
        short8 b8 = *(const short8*)&Ks[krj*256 + ((dc*32 + lg*8) ^ ((krj & 7) << 3))];
        sc[j] = mfma16(qf[dc], b8, sc[j]);
      }
    }
    // p = exp(s - m); write attn = p/l; stash p (bf16, swizzled) for PV
    #pragma unroll
    for (int r = 0; r < 4; ++r){
      const int qq = q0 + w*16 + lg*4 + r;
      const int row = lg*4 + r;
      float* wrp = Wout + ((size_t)bh * SS + qq) * SS;
      #pragma unroll
      for (int j = 0; j < 4; ++j){
        const int kk = k0 + j*16 + lr;
        float p = (kk <= qq) ? exp2f((sc[j][r] - mrow[r]) * L2E) : 0.f;
        wrp[kk] = p * il[r];
        int chunk = j*2 + (lr >> 3);
        Ps[w][row*64 + ((chunk ^ (row & 7)) << 3) + (lr & 7)] = f2bf(p);
      }
    }
    // PV: out[16q][256d] += P[16q][64k] x V[64k][256d] (wave-local Ps, no barrier)
    #pragma unroll
    for (int kc = 0; kc < 2; ++kc){
      short8 pa = *(const short8*)&Ps[w][lr*64 + (((kc*4 + lg) ^ (lr & 7)) << 3)];
      #pragma unroll
      for (int nf = 0; nf < 16; ++nf){
        int dr = nf*16 + lr;
        short8 vb = *(const short8*)&Vs[dr*64 + (((kc*4 + lg) ^ (dr & 7)) << 3)];
        oacc[nf] = mfma16(pa, vb, oacc[nf]);
      }
    }
    __syncthreads();
  }
  // zero-fill strictly-above-block columns (exact zeros in reference too)
  const int zc0 = q0 + 64;
  if (zc0 < SS){
    const int quads = (SS - zc0) >> 2;
    const float4 z4 = make_float4(0.f, 0.f, 0.f, 0.f);
    for (int rr = w; rr < 64; rr += 4){
      float* rowp = Wout + ((size_t)bh*SS + q0 + rr)*SS + zc0;
      for (int c = l; c < quads; c += 64)
        *(float4*)&rowp[c*4] = z4;
    }
  }
  // write PV result (scaled by 1/l) as bf16 rows (b,s) x cols h*256+d
  #pragma unroll
  for (int nf = 0; nf < 16; ++nf){
    #pragma unroll
    for (int r = 0; r < 4; ++r){
      int qq = q0 + w*16 + lg*4 + r;
      int d  = nf*16 + lr;
      Ows[((size_t)(b*SS) + qq)*2048 + h*256 + d] = f2bf(oacc[nf][r] * il[r]);
    }
  }
}

// ---------------- host launch ----------------
extern "C" void kernel_launch(void* const* d_in, const int* in_sizes, int n_in,
                              void* d_out, int out_size, void* d_ws, size_t ws_size,
                              hipStream_t stream){
  const float* H  = (const float*)d_in[0];
  const int*  pos = (const int*)d_in[2];
  const float* Wq = (const float*)d_in[3];
  const float* Wk = (const float*)d_in[4];
  const float* Wv = (const float*)d_in[5];
  const float* Wo = (const float*)d_in[6];
  float* out = (float*)d_out;
  float* Wts = out + (size_t)BB*SS*HIDD;          // attn_weights region (also early scratch)

  // Scratch inside the (later fully overwritten) weights region: Hb 16MB + Wt 10MB
  ushort* Hb = (ushort*)Wts;
  ushort* Wt = Hb + (size_t)BB*SS*HIDD;

  char* ws = (char*)d_ws;
  size_t off = 0;
  auto alloc = [&](size_t bytes)->char*{
    char* p = ws + off; off += (bytes + 255) & ~(size_t)255; return p;
  };
  ushort* Wot   = (ushort*)alloc((size_t)2048*2048*2);
  ushort* Qr    = (ushort*)alloc((size_t)BB*SS*NHH*HDD*2);
  ushort* Kr    = (ushort*)alloc((size_t)BB*SS*HDD*2);
  ushort* Vr    = (ushort*)alloc((size_t)BB*SS*HDD*2);
  ushort* Vt    = (ushort*)alloc((size_t)BB*HDD*SS*2);
  float2* cst   = (float2*)alloc((size_t)BB*SS*128*8);
  float*  mpart = (float*)alloc((size_t)4*BB*NHH*SS*4);
  float*  lpart = (float*)alloc((size_t)4*BB*NHH*SS*4);
  float*  mfin  = (float*)alloc((size_t)BB*NHH*SS*4);
  float*  invl  = (float*)alloc((size_t)BB*NHH*SS*4);
  ushort* Ows   = (ushort*)alloc((size_t)BB*SS*NHH*HDD*2);
  (void)ws_size; (void)in_sizes; (void)n_in; (void)out_size;

  k_prep<<<2048, 256, 0, stream>>>(H, Hb, pos, cst);
  k_transAll<<<2304, 256, 0, stream>>>(Wq, Wk, Wv, Wo, Wt, Wot);
  // [Q|K|V] = Hb @ Wt^T ; scatter epilogue (V row-major)
  k_gemm<<<dim3(20,32), 256, 0, stream>>>(Hb, Wt, 64, 1, nullptr, Qr, Kr, Vr);
  k_transV<<<256, 256, 0, stream>>>(Vr, Vt);
  k_rope<<<(BB*SS*NHH*128 + BB*SS*128)/256, 256, 0, stream>>>(Qr, Kr, cst);
  k_stats<<<dim3(32,4,16), 256, 0, stream>>>(Qr, Kr, mpart, lpart);
  k_merge<<<(BB*NHH*SS)/256, 256, 0, stream>>>(mpart, lpart, mfin, invl);
  k_attn2<<<dim3(32,16), 256, 0, stream>>>(Qr, Kr, Vt, mfin, invl, Wts, Ows);
  // attn_output = Ows @ Wot^T
  k_gemm<<<dim3(16,32), 256, 0, stream>>>(Ows, Wot, 64, 0, out, nullptr, nullptr, nullptr);
}